// Round 1
// baseline (384.665 us; speedup 1.0000x reference)
//
#include <hip/hip_runtime.h>
#include <hip/hip_bf16.h>

#define B_    32
#define C_    128
#define H_    56
#define W_    56
#define OUT_  256
#define K_    4
#define HID_  64
#define HW_   (H_*W_)        // 3136
#define KV_   (C_*9)         // 1152
#define PH_   58
#define PW_   58
#define PP_   (PH_*PW_)      // 3364 padded pixels per sample

typedef __attribute__((ext_vector_type(8))) short short8_t;   // 8 x bf16
typedef __attribute__((ext_vector_type(4))) float float4_t;

typedef __hip_bfloat16 bf16;

__device__ __forceinline__ short f2bf(float v) {
    union { bf16 h; short s; } u; u.h = __float2bfloat16(v); return u.s;
}

typedef __attribute__((address_space(1))) const unsigned int* gas_t;
typedef __attribute__((address_space(3))) unsigned int* las_t;

// async global->LDS, 16 B per lane; LDS dest = wave-uniform base + lane*16
__device__ __forceinline__ void gl_lds16(const short* g, short* l) {
    __builtin_amdgcn_global_load_lds((gas_t)(const void*)g, (las_t)(void*)l, 16, 0, 0);
}

// ---------------------------------------------------------------------------
// Kernel 1: fused  x -> zero-padded xTp[b][58*58][c] (bf16)  +  global avg pool
// (pooled must be zeroed before launch; accumulated with atomics)
// ---------------------------------------------------------------------------
__global__ __launch_bounds__(256) void dc_xt(const float* __restrict__ x,
                                             short* __restrict__ xTp,
                                             float* __restrict__ pooled) {
    int b = blockIdx.y, n0 = blockIdx.x * 128;   // 27 x-blocks cover 3456 >= 3364
    __shared__ short t[C_][130];
    int lane = threadIdx.x & 63;
    for (int i = threadIdx.x; i < C_*128; i += 256) {
        int c = i >> 7, nn = i & 127;            // c is wave-uniform per iteration
        int pp = n0 + nn;
        int py = pp / PW_, px = pp - py*PW_;
        bool valid = (pp < PP_) & (py >= 1) & (py <= H_) & (px >= 1) & (px <= W_);
        float v = valid ? x[((size_t)b*C_ + c)*HW_ + (py-1)*W_ + (px-1)] : 0.f;
        t[c][nn] = f2bf(v);
        // pool: wave-reduce v (c uniform across the wave here)
        float s = v;
        for (int off = 32; off > 0; off >>= 1) s += __shfl_down(s, off, 64);
        if (lane == 0 && s != 0.f) atomicAdd(&pooled[b*C_ + c], s);
    }
    __syncthreads();
    for (int i = threadIdx.x; i < 64*128; i += 256) {
        int nn = i >> 6, c2 = (i & 63) * 2;
        int pp = n0 + nn;
        if (pp < PP_) {
            union { unsigned short u[2]; unsigned v; } pk;
            pk.u[0] = (unsigned short)t[c2][nn];
            pk.u[1] = (unsigned short)t[c2+1][nn];
            *(unsigned*)&xTp[((size_t)b*PP_ + pp)*C_ + c2] = pk.v;
        }
    }
}

// ---------------------------------------------------------------------------
// Kernel 2: attn = softmax(relu((pooled/HW)@fc1^T)@fc2^T)
// ---------------------------------------------------------------------------
__global__ __launch_bounds__(64) void dc_attn(const float* __restrict__ pooled,
                                              const float* __restrict__ fc1w,
                                              const float* __restrict__ fc1b,
                                              const float* __restrict__ fc2w,
                                              const float* __restrict__ fc2b,
                                              float* __restrict__ attn) {
    int b = blockIdx.x, h = threadIdx.x;
    __shared__ float pl[C_];
    __shared__ float hdn[HID_];
    __shared__ float logit[K_];
    pl[h]      = pooled[b*C_ + h]      * (1.0f / HW_);
    pl[h + 64] = pooled[b*C_ + 64 + h] * (1.0f / HW_);
    __syncthreads();
    float s = fc1b[h];
    #pragma unroll 8
    for (int c = 0; c < C_; ++c) s += pl[c] * fc1w[h*C_ + c];
    hdn[h] = fmaxf(s, 0.f);
    __syncthreads();
    if (h < K_) {
        float t = fc2b[h];
        #pragma unroll 8
        for (int j = 0; j < HID_; ++j) t += hdn[j] * fc2w[h*HID_ + j];
        logit[h] = t;
    }
    __syncthreads();
    if (h == 0) {
        float m = fmaxf(fmaxf(logit[0], logit[1]), fmaxf(logit[2], logit[3]));
        float e0 = __expf(logit[0]-m), e1 = __expf(logit[1]-m);
        float e2 = __expf(logit[2]-m), e3 = __expf(logit[3]-m);
        float inv = 1.0f / (e0+e1+e2+e3);
        attn[b*K_+0]=e0*inv; attn[b*K_+1]=e1*inv;
        attn[b*K_+2]=e2*inv; attn[b*K_+3]=e3*inv;
    }
}

// ---------------------------------------------------------------------------
// Kernel 3: weight synthesis  Ws[b][o][k=tap*128+c] (bf16)
// grid (OUT_, 4): block = (o, group of 8 samples); bank row staged in LDS once.
// ---------------------------------------------------------------------------
__global__ __launch_bounds__(256) void dc_wsynth(const float* __restrict__ bank,
                                                 const float* __restrict__ attn,
                                                 bf16* __restrict__ Ws) {
    int o = blockIdx.x;
    int b0 = blockIdx.y * 8;
    __shared__ float wb[4*KV_];
    for (int i = threadIdx.x; i < 4*KV_; i += 256) {
        int kk = i / KV_, r = i - kk*KV_;
        wb[i] = bank[((size_t)kk*OUT_ + o)*KV_ + r];
    }
    __syncthreads();
    for (int bi = 0; bi < 8; ++bi) {
        int b = b0 + bi;
        float a0 = attn[b*K_+0], a1 = attn[b*K_+1];
        float a2 = attn[b*K_+2], a3 = attn[b*K_+3];
        unsigned* dst = (unsigned*)&Ws[((size_t)b*OUT_ + o)*KV_];
        for (int ii = threadIdx.x; ii < KV_/2; ii += 256) {
            int i0 = 2*ii;
            int tap0 = i0 >> 7, c0 = i0 & 127;
            int i1 = i0 + 1;
            int tap1 = i1 >> 7, c1 = i1 & 127;
            float v0 = a0*wb[c0*9+tap0] + a1*wb[KV_+c0*9+tap0]
                     + a2*wb[2*KV_+c0*9+tap0] + a3*wb[3*KV_+c0*9+tap0];
            float v1 = a0*wb[c1*9+tap1] + a1*wb[KV_+c1*9+tap1]
                     + a2*wb[2*KV_+c1*9+tap1] + a3*wb[3*KV_+c1*9+tap1];
            union { unsigned short u[2]; unsigned v; } pk;
            pk.u[0] = (unsigned short)f2bf(v0);
            pk.u[1] = (unsigned short)f2bf(v1);
            dst[ii] = pk.v;
        }
    }
}

// ---------------------------------------------------------------------------
// Kernel 4: LDS-staged implicit GEMM, double-buffered 2-phase (T3-minimum).
//   C[b][m][n] = sum_{tap,c} Ws[b][m][tap*128+c] * xTp[b][pad(n)+doffp(tap)][c]
// Block 128m x 128n, 4 waves 2x2 (64x64 each). Per K-step (64 k):
//   issue next step's 8 global_load_lds -> compute current buffer ->
//   ONE __syncthreads (vmcnt(0)+lgkmcnt(0) drain publishes prefetch AND
//   retires current reads). Staging latency overlaps MFMA+ds_read.
// LDS 64 KB (2 buffers) -> 2 blocks/CU.
// Grid flattened to 1600 blocks with bijective XCD-chunk swizzle (1600%8==0):
// one XCD owns 4 consecutive samples (A-panels + xTp L2-resident per XCD).
// ---------------------------------------------------------------------------
__global__ __launch_bounds__(256) void dc_gemm(const short* __restrict__ Ws,
                                               const short* __restrict__ xTp,
                                               float* __restrict__ out) {
    // ---- bijective XCD swizzle over the flat 1600-block grid ----
    const int nwg = 25 * 2 * B_;            // 1600
    const int cpx = nwg >> 3;               // 200 blocks per XCD chunk
    int orig = blockIdx.x;
    int swz  = (orig & 7) * cpx + (orig >> 3);
    const int bx  = swz % 25;               // n-block (fastest within chunk)
    const int byz = swz / 25;
    const int by  = byz & 1;                // m-block
    const int b   = byz >> 1;               // sample

    const int m0 = by * 128;
    const int n0 = bx * 128;
    const int tid  = threadIdx.x;
    const int lane = tid & 63;
    const int wv   = tid >> 6;
    const int wm   = wv & 1, wn = wv >> 1;
    const int l16  = lane & 15, quad = lane >> 4;

    __shared__ short lA[2][8192];   // 2 x 16 KB
    __shared__ short lB[2][8192];   // 2 x 16 KB

    // --- staging source pointers: wave wv stages segments t = 4*wv + j ---
    const short* aG[4];
    const short* bG[4];
    int segOff[4];
    #pragma unroll
    for (int j = 0; j < 4; ++j) {
        int t = 4*wv + j;
        int row = (t >> 1) * 16 + l16;
        int kq  = t & 1;
        aG[j] = Ws + ((size_t)b*OUT_ + m0 + row)*KV_ + kq*32 + quad*8;
        int n = n0 + row;
        int idc = min(n, HW_ - 1);
        int y = idc / W_, xx2 = idc - y * W_;
        int pbc = (y + 1) * PW_ + (xx2 + 1);
        bG[j] = xTp + ((size_t)b*PP_ + pbc)*C_ + kq*32 + quad*8;
        segOff[j] = t * 512;
    }

    int nidx[4];
    #pragma unroll
    for (int ni = 0; ni < 4; ++ni)
        nidx[ni] = n0 + wn*64 + ni*16 + l16;

    float4_t acc[4][4];
    #pragma unroll
    for (int mi = 0; mi < 4; ++mi)
        #pragma unroll
        for (int ni = 0; ni < 4; ++ni)
            acc[mi][ni] = (float4_t){0.f, 0.f, 0.f, 0.f};

    // stage K-step s (s = tap*2 + half, 18 steps of 64 k) into buffer buf
    auto stage = [&](int s, int buf) {
        int tap = s >> 1;
        int ty = tap / 3, tx = tap - 3*ty;
        int doff = ((ty - 1) * PW_ + (tx - 1)) * C_;   // B row shift (shorts)
        int ka = s * 64;                                // A column base
        int cb = (s & 1) * 64;                          // B column base
        #pragma unroll
        for (int j = 0; j < 4; ++j) {
            gl_lds16(aG[j] + ka,        lA[buf] + segOff[j]);
            gl_lds16(bG[j] + doff + cb, lB[buf] + segOff[j]);
        }
    };

    auto compute = [&](int buf) {
        #pragma unroll
        for (int kq = 0; kq < 2; ++kq) {
            short8_t af[4], bf[4];
            #pragma unroll
            for (int mi = 0; mi < 4; ++mi)
                af[mi] = *(const short8_t*)(lA[buf] + ((wm*4+mi)*2 + kq)*512 + lane*8);
            #pragma unroll
            for (int ni = 0; ni < 4; ++ni)
                bf[ni] = *(const short8_t*)(lB[buf] + ((wn*4+ni)*2 + kq)*512 + lane*8);
            #pragma unroll
            for (int mi = 0; mi < 4; ++mi)
                #pragma unroll
                for (int ni = 0; ni < 4; ++ni)
                    acc[mi][ni] = __builtin_amdgcn_mfma_f32_16x16x32_bf16(
                        af[mi], bf[ni], acc[mi][ni], 0, 0, 0);
        }
    };

    stage(0, 0);
    __syncthreads();                 // publish step 0
    int cur = 0;
    for (int s = 0; s < 18; ++s) {
        if (s < 17) stage(s + 1, cur ^ 1);   // prefetch next (overlaps compute)
        compute(cur);
        __syncthreads();             // vmcnt(0): prefetch landed; lgkmcnt(0): reads done
        cur ^= 1;
    }

    // Epilogue: D[m = quad*4 + reg][n = l16] per 16x16 tile
    const size_t obase = (size_t)b * OUT_ * HW_;
    #pragma unroll
    for (int mi = 0; mi < 4; ++mi) {
        int m = m0 + wm*64 + mi*16 + quad*4;
        #pragma unroll
        for (int ni = 0; ni < 4; ++ni) {
            int n = nidx[ni];
            if (n < HW_) {
                float* op = out + obase + (size_t)m * HW_ + n;
                #pragma unroll
                for (int r = 0; r < 4; ++r)
                    op[(size_t)r * HW_] = acc[mi][ni][r];
            }
        }
    }
}

// ---------------------------------------------------------------------------
extern "C" void kernel_launch(void* const* d_in, const int* in_sizes, int n_in,
                              void* d_out, int out_size, void* d_ws, size_t ws_size,
                              hipStream_t stream) {
    const float* x    = (const float*)d_in[0];
    const float* bank = (const float*)d_in[1];
    const float* fc1w = (const float*)d_in[2];
    const float* fc1b = (const float*)d_in[3];
    const float* fc2w = (const float*)d_in[4];
    const float* fc2b = (const float*)d_in[5];
    float* out = (float*)d_out;

    char* ws = (char*)d_ws;
    float* pooled = (float*)ws;                          // 16 KB (zeroed below)
    float* attn   = (float*)(ws + 16*1024);              // 512 B
    bf16*  Ws     = (bf16*) (ws + 32*1024);              // 18,874,368 B
    short* xTp    = (short*)(ws + 32*1024 + 18874368);   // 27,557,888 B

    hipMemsetAsync(pooled, 0, B_*C_*sizeof(float), stream);
    dc_xt    <<<dim3(27, B_), 256, 0, stream>>>(x, xTp, pooled);
    dc_attn  <<<B_,     64, 0, stream>>>(pooled, fc1w, fc1b, fc2w, fc2b, attn);
    dc_wsynth<<<dim3(OUT_, 4), 256, 0, stream>>>(bank, attn, Ws);
    dc_gemm  <<<dim3(1600), 256, 0, stream>>>((const short*)Ws, xTp, out);
}